// Round 8
// baseline (455.131 us; speedup 1.0000x reference)
//
#include <hip/hip_runtime.h>
#include <hip/hip_bf16.h>

// Problem constants (B=2, S=2048, HID=2048, NH=32, NKV=8, D=64, M=256, CHUNK=128)
#define SEQ   2048
#define NHEAD 32
#define NKVH  8
#define DH    64
#define MFEAT 256
#define NCH   16
#define EPSF  1e-6f

typedef __hip_bfloat16 bf16;
typedef unsigned short u16;
typedef __attribute__((ext_vector_type(8))) short short8;   // 8 bf16 (4 VGPRs)
typedef __attribute__((ext_vector_type(4))) float f32x4;    // 4 fp32 acc

__device__ __forceinline__ float b2f(bf16 x){ return __bfloat162float(x); }
__device__ __forceinline__ bf16  f2b(float x){ return __float2bfloat16(x); }
__device__ __forceinline__ u16   f2u(float x){ bf16 h = __float2bfloat16(x); return *reinterpret_cast<u16*>(&h); }

// dtype probe: d_in[1] is cos; cos[0]==1.0 exactly.
// fp32 -> word0 = 0x3F800000 (low16==0). bf16-packed -> low16!=0.
__device__ __forceinline__ bool probe_f32(const unsigned* __restrict__ p){
  return (p[0] & 0xFFFFu) == 0u;
}
__device__ __forceinline__ float loadIn(const void* __restrict__ ptr, size_t idx, bool f32){
  return f32 ? ((const float*)ptr)[idx] : b2f(((const bf16*)ptr)[idx]);
}

// async 16B global -> LDS (wave-uniform LDS base; HW adds lane*16)
__device__ __forceinline__ void cp16(u16* lds, const u16* g){
  __builtin_amdgcn_global_load_lds((const __attribute__((address_space(1))) unsigned*)g,
      (__attribute__((address_space(3))) unsigned*)lds, 16, 0, 0);
}

#define MFMA16(a,b,c) __builtin_amdgcn_mfma_f32_16x16x32_bf16(a,b,c,0,0,0)
#define SBAR()  do { __builtin_amdgcn_s_barrier(); __builtin_amdgcn_sched_barrier(0); } while(0)

// ---------------------------------------------------------------------------
// dtype convert: src (fp32 or bf16 per probe) -> bf16 (u16) dst.
// Vectorized: 8 elems/thread (f32: 2x float4 -> short8; bf16: short8 copy).
// ---------------------------------------------------------------------------
__device__ __forceinline__ void conv8(const void* __restrict__ src, size_t i8,
                                      u16* __restrict__ dst, size_t o8, bool f32in)
{
  if (f32in){
    const float4* s = (const float4*)src;
    float4 a = s[i8*2], b = s[i8*2+1];
    u16 t[8] = {f2u(a.x),f2u(a.y),f2u(a.z),f2u(a.w),
                f2u(b.x),f2u(b.y),f2u(b.z),f2u(b.w)};
    *(short8*)&dst[o8*8] = *(const short8*)t;
  } else {
    *(short8*)&dst[o8*8] = ((const short8*)src)[i8];
  }
}

__global__ __launch_bounds__(256) void conv_kernel(const void* __restrict__ src,
    u16* __restrict__ dst, const unsigned* __restrict__ probe)
{
  const bool f32in = probe_f32(probe);
  size_t i = (size_t)blockIdx.x*256 + threadIdx.x;
  conv8(src, i, dst, i, f32in);
}

// fused Wq|Wk|Wv convert -> contiguous wqkv (8-elem units: 524288|131072|131072)
__global__ __launch_bounds__(256) void wconv_kernel(const void* __restrict__ Wq,
    const void* __restrict__ Wk, const void* __restrict__ Wv,
    u16* __restrict__ dst, const unsigned* __restrict__ probe)
{
  const bool f32in = probe_f32(probe);
  size_t i = (size_t)blockIdx.x*256 + threadIdx.x;
  const void* src; size_t off;
  if (i < 524288){ src = Wq; off = i; }
  else if (i < 655360){ src = Wk; off = i - 524288; }
  else { src = Wv; off = i - 655360; }
  conv8(src, off, dst, i, f32in);
}

// ---------------------------------------------------------------------------
// MFMA GEMM (round-3 structure, best measured): C[r,c] = sum_k A[r,k]*W[c,k];
// A,W row-major bf16 (u16).  Tile 256x128, BK=64, 8 waves (4M x 2N ->
// per-wave 64x64, acc[4][4]).  3-slot pipeline, counted s_waitcnt vmcnt(6)
// once per K-tile (never 0 until last tile).  K-tile body in 4 phases:
//   phase p: { ds_read quad frags | 2 stage cp16 } -> barrier ->
//            setprio(1) -> 8 MFMA -> setprio(0) -> barrier
// T2 LDS XOR-swizzle (col ^= (row&7)<<3) via pre-swizzled global source +
// swizzled ds_read.  XCD-aware block swizzle.
// mode 0: outAny[r*N+c] (dtype probed f32/bf16)
// mode 1: qkv scatter -> oq/ok/ov fp32 head-major [b,h,s,d], RoPE+dn fused
//         for q,k (each wave's 64-col span is one head; d^32 partner = nt^2).
// ---------------------------------------------------------------------------
__global__ __launch_bounds__(512) void gemm_mfma(const u16* __restrict__ A,
    const u16* __restrict__ W, float* __restrict__ oq, float* __restrict__ ok,
    float* __restrict__ ov, void* __restrict__ outAny, int K, int N, int mode,
    const void* __restrict__ cosg, const void* __restrict__ sing,
    const unsigned* __restrict__ probe)
{
  __shared__ __align__(16) u16 sA[3][16384];   // 3 x 256x64
  __shared__ __align__(16) u16 sB[3][8192];    // 3 x 128x64
  const int tid = threadIdx.x;
  const int lane = tid & 63, wave = tid >> 6;

  // XCD-aware swizzle: contiguous chunk of logical tiles per XCD.
  const int nbx = gridDim.x;
  const int nwg = nbx * gridDim.y;
  int id = blockIdx.y * nbx + blockIdx.x;
  int sw = id;
  if ((nwg & 7) == 0) sw = (id & 7) * (nwg >> 3) + (id >> 3);
  const int bx = sw % nbx, by = sw / nbx;
  const int c0 = bx*128, r0 = by*256;

  const int wm = wave >> 1, wn = wave & 1;
  f32x4 acc[4][4] = {};

  // --- staging: 6 x cp16 per thread per K-tile (A:4, B:2), pre-swizzled src.
  const int rl  = lane >> 3;
  const int swzE = ((lane & 7) ^ rl) << 3;
  const u16* gA = A + (size_t)(r0 + wave*8 + rl)*K + swzE;
  const u16* gB = W + (size_t)(c0 + wave*8 + rl)*K + swzE;
  const int aDst = wave*512;   // u16 offset in buf; +i*4096 per 64-row group
  const int bDst = wave*512;

  // --- frag ds_read offsets (u16): row*64 + (col ^ ((row&7)<<3)); row&7==lane&7
  const int rowA = (wm*64 + (lane&15))*64;
  const int rowB = (wn*64 + (lane&15))*64;
  const int colS = (((lane>>4)*8) ^ ((lane&7)<<3));   // ks=0 ; ks=1 -> ^32

  const int nk = K >> 6;   // K=2048 -> 32 K-tiles

  #define STAGE_ALL(buf, t) do { const int k0_ = (t)*64;                  \
    cp16(&sA[buf][aDst],         gA + k0_);                               \
    cp16(&sA[buf][aDst + 4096],  gA + (size_t)64*K  + k0_);               \
    cp16(&sA[buf][aDst + 8192],  gA + (size_t)128*K + k0_);               \
    cp16(&sA[buf][aDst + 12288], gA + (size_t)192*K + k0_);               \
    cp16(&sB[buf][bDst],         gB + k0_);                               \
    cp16(&sB[buf][bDst + 4096],  gB + (size_t)64*K  + k0_); } while(0)

  // prologue: tiles 0,1 in flight (12 loads)
  STAGE_ALL(0, 0);
  STAGE_ALL(1, 1);

  int cur = 0;
  for (int t = 0; t < nk; ++t) {
    // own tile-t loads retired (newest 6 = tile t+1 stay in flight);
    // barrier makes that true for ALL waves' tile-t loads.
    if (t < nk-1) asm volatile("s_waitcnt vmcnt(6)" ::: "memory");
    else          asm volatile("s_waitcnt vmcnt(0)" ::: "memory");
    SBAR();

    int sb = cur + 2; if (sb >= 3) sb -= 3;
    const int k0s = (t + 2) * 64;
    const bool st = (t + 2 < nk);
    const u16* bA_ = sA[cur];
    const u16* bB_ = sB[cur];

    short8 a01[2][2], a23[2][2], b01[2][2], b23[2][2];

    // ---- phase 0: read A01+B01 ; stage A groups 0,1 ; MFMA mt01 x nt01
    #pragma unroll
    for (int mt=0;mt<2;++mt){
      a01[mt][0] = *(const short8*)(bA_ + rowA + mt*1024 + colS);
      a01[mt][1] = *(const short8*)(bA_ + rowA + mt*1024 + (colS^32));
    }
    #pragma unroll
    for (int nt=0;nt<2;++nt){
      b01[nt][0] = *(const short8*)(bB_ + rowB + nt*1024 + colS);
      b01[nt][1] = *(const short8*)(bB_ + rowB + nt*1024 + (colS^32));
    }
    if (st){ cp16(&sA[sb][aDst], gA + k0s);
             cp16(&sA[sb][aDst + 4096], gA + (size_t)64*K + k0s); }
    SBAR();
    __builtin_amdgcn_s_setprio(1);
    #pragma unroll
    for (int mt=0;mt<2;++mt)
      #pragma unroll
      for (int nt=0;nt<2;++nt){
        acc[mt][nt] = MFMA16(a01[mt][0], b01[nt][0], acc[mt][nt]);
        acc[mt][nt] = MFMA16(a01[mt][1], b01[nt][1], acc[mt][nt]);
      }
    __builtin_amdgcn_s_setprio(0);
    SBAR();

    // ---- phase 1: read B23 ; stage A groups 2,3 ; MFMA mt01 x nt23
    #pragma unroll
    for (int nt=0;nt<2;++nt){
      b23[nt][0] = *(const short8*)(bB_ + rowB + (nt+2)*1024 + colS);
      b23[nt][1] = *(const short8*)(bB_ + rowB + (nt+2)*1024 + (colS^32));
    }
    if (st){ cp16(&sA[sb][aDst + 8192],  gA + (size_t)128*K + k0s);
             cp16(&sA[sb][aDst + 12288], gA + (size_t)192*K + k0s); }
    SBAR();
    __builtin_amdgcn_s_setprio(1);
    #pragma unroll
    for (int mt=0;mt<2;++mt)
      #pragma unroll
      for (int nt=0;nt<2;++nt){
        acc[mt][nt+2] = MFMA16(a01[mt][0], b23[nt][0], acc[mt][nt+2]);
        acc[mt][nt+2] = MFMA16(a01[mt][1], b23[nt][1], acc[mt][nt+2]);
      }
    __builtin_amdgcn_s_setprio(0);
    SBAR();

    // ---- phase 2: read A23 ; stage B groups 0,1 ; MFMA mt23 x nt23
    #pragma unroll
    for (int mt=0;mt<2;++mt){
      a23[mt][0] = *(const short8*)(bA_ + rowA + (mt+2)*1024 + colS);
      a23[mt][1] = *(const short8*)(bA_ + rowA + (mt+2)*1024 + (colS^32));
    }
    if (st){ cp16(&sB[sb][bDst], gB + k0s);
             cp16(&sB[sb][bDst + 4096], gB + (size_t)64*K + k0s); }
    SBAR();
    __builtin_amdgcn_s_setprio(1);
    #pragma unroll
    for (int mt=0;mt<2;++mt)
      #pragma unroll
      for (int nt=0;nt<2;++nt){
        acc[mt+2][nt+2] = MFMA16(a23[mt][0], b23[nt][0], acc[mt+2][nt+2]);
        acc[mt+2][nt+2] = MFMA16(a23[mt][1], b23[nt][1], acc[mt+2][nt+2]);
      }
    __builtin_amdgcn_s_setprio(0);
    SBAR();

    // ---- phase 3: no reads/stages ; MFMA mt23 x nt01 (reuse a23, b01)
    __builtin_amdgcn_s_setprio(1);
    #pragma unroll
    for (int mt=0;mt<2;++mt)
      #pragma unroll
      for (int nt=0;nt<2;++nt){
        acc[mt+2][nt] = MFMA16(a23[mt][0], b01[nt][0], acc[mt+2][nt]);
        acc[mt+2][nt] = MFMA16(a23[mt][1], b01[nt][1], acc[mt+2][nt]);
      }
    __builtin_amdgcn_s_setprio(0);
    // phase-3 end barrier = next iteration's top barrier

    cur = (cur == 2) ? 0 : cur + 1;
  }
  #undef STAGE_ALL

  const int rbase = r0 + wm*64 + (lane>>4)*4;   // + mt*16 + rg
  const int cbase = c0 + wn*64 + (lane&15);     // + nt*16
  if (mode == 0) {
    const bool f32o = probe_f32(probe);
    #pragma unroll
    for (int mt=0;mt<4;++mt)
      #pragma unroll
      for (int nt=0;nt<4;++nt)
        #pragma unroll
        for (int rg=0;rg<4;++rg){
          int r = rbase + mt*16 + rg, c = cbase + nt*16;
          float v = acc[mt][nt][rg];
          if (f32o) ((float*)outAny)[(size_t)r*N + c] = v;
          else      ((u16*)outAny)[(size_t)r*N + c] = f2u(v);
        }
  } else {
    const bool f32in = probe_f32(probe);
    const float dn = 0.3535533905932738f;  // 64^-0.25
    #pragma unroll
    for (int nt=0;nt<4;++nt){
      int cc = cbase + nt*16;
      float* dst; int H2, cl; bool isv = false;
      if (cc < 2048){ dst = oq; H2 = 32; cl = cc; }
      else if (cc < 2560){ dst = ok; H2 = 8; cl = cc - 2048; }
      else { dst = ov; H2 = 8; cl = cc - 2560; isv = true; }
      int hh = cl>>6, dd = cl&63;
      float sgn = (dd < 32) ? -1.f : 1.f;
      #pragma unroll
      for (int mt=0;mt<4;++mt)
        #pragma unroll
        for (int rg=0;rg<4;++rg){
          int r = rbase + mt*16 + rg;
          int bb = r>>11, s = r&2047;
          float v = acc[mt][nt][rg];
          if (!isv){
            float vp = acc[mt][nt^2][rg];
            size_t ci = ((size_t)bb*SEQ + s)*DH + dd;
            float cv = loadIn(cosg, ci, f32in);
            float sv = loadIn(sing, ci, f32in);
            v = (v*cv + sgn*vp*sv) * dn;
          }
          dst[(((size_t)bb*H2 + hh)*SEQ + s)*DH + dd] = v;
        }
    }
  }
}

// ---------------------------------------------------------------------------
// phi via MFMA: xp = xn[rows x 64] @ proj[256 x 64]^T, K=64.
// 64 rows/block, 4 waves x (1 row-tile x 16 col-tiles).
// mode 0: q — rowwise stab, exp, write phi
// mode 1: k pass A — rowwise max -> rmaxk
// mode 2: k pass B — exp with global stabk, write phi
// Output path: stage 64x256 tile in LDS (reusing sP, granule-XOR
// g^=((row>>2)&3)<<2) then 8 coalesced short8 stores/thread.
// ---------------------------------------------------------------------------
__global__ __launch_bounds__(256) void phi_mfma(const float* __restrict__ xn,
    const u16* __restrict__ projb, float* __restrict__ rmaxk,
    const float* __restrict__ stabk, u16* __restrict__ phi, int mode)
{
  __shared__ __align__(16) u16 sA[64*80];
  __shared__ __align__(16) u16 sP[256*80];
  __shared__ float sq[64];
  const int tid = threadIdx.x, lane = tid & 63, wave = tid >> 6;
  const size_t row0 = (size_t)blockIdx.x * 64;

  // stage proj: 2048 short8 vectors -> [m][80] padded
  #pragma unroll
  for (int l = 0; l < 8; ++l){
    int v8 = tid + l*256;
    int off = v8*8; int m = off>>6, d = off&63;
    *(short8*)&sP[m*80 + d] = ((const short8*)projb)[v8];
  }
  // stage xn rows fp32 -> bf16 + sq partials (thread = row tid>>2, quarter tid&3)
  {
    int r = tid >> 2, qq = tid & 3;
    const float* src = xn + (row0 + r)*DH + qq*16;
    float s = 0.f;
    u16 tmp[16];
    #pragma unroll
    for (int i=0;i<16;i+=4){
      float4 v4 = *(const float4*)&src[i];
      s += v4.x*v4.x + v4.y*v4.y + v4.z*v4.z + v4.w*v4.w;
      tmp[i] = f2u(v4.x); tmp[i+1] = f2u(v4.y); tmp[i+2] = f2u(v4.z); tmp[i+3] = f2u(v4.w);
    }
    *(short8*)&sA[r*80 + qq*16]     = *(short8*)&tmp[0];
    *(short8*)&sA[r*80 + qq*16 + 8] = *(short8*)&tmp[8];
    s += __shfl_xor(s, 1, 64);
    s += __shfl_xor(s, 2, 64);
    if (qq == 0) sq[r] = 0.5f*s;
  }
  __syncthreads();

  // MFMA: wave owns rows wave*16..+15; 16 col-tiles, 2 k-steps
  f32x4 acc[16] = {};
  const u16* pA = &sA[(wave*16 + (lane&15))*80 + (lane>>4)*8];
  short8 af0 = *(const short8*)(pA);
  short8 af1 = *(const short8*)(pA + 32);
  #pragma unroll
  for (int nt=0; nt<16; ++nt){
    const u16* pB = &sP[(nt*16 + (lane&15))*80 + (lane>>4)*8];
    short8 b0 = *(const short8*)(pB);
    short8 b1 = *(const short8*)(pB + 32);
    acc[nt] = MFMA16(af0, b0, acc[nt]);
    acc[nt] = MFMA16(af1, b1, acc[nt]);
  }

  // rowwise max across 256 cols (in-reg over nt, then 16-lane butterfly)
  float mx[4];
  #pragma unroll
  for (int rg=0; rg<4; ++rg){
    float m = acc[0][rg];
    #pragma unroll
    for (int nt=1; nt<16; ++nt) m = fmaxf(m, acc[nt][rg]);
    m = fmaxf(m, __shfl_xor(m, 1, 64));
    m = fmaxf(m, __shfl_xor(m, 2, 64));
    m = fmaxf(m, __shfl_xor(m, 4, 64));
    m = fmaxf(m, __shfl_xor(m, 8, 64));
    mx[rg] = m;
  }
  const int rloc = wave*16 + (lane>>4)*4;   // + rg
  if (mode == 1){
    if ((lane & 15) == 0){
      #pragma unroll
      for (int rg=0;rg<4;++rg) rmaxk[row0 + rloc + rg] = mx[rg];
    }
    return;
  }
  float stab[4];
  if (mode == 0){
    #pragma unroll
    for (int rg=0;rg<4;++rg) stab[rg] = mx[rg];
  } else {
    float s = stabk[row0 >> 11];
    #pragma unroll
    for (int rg=0;rg<4;++rg) stab[rg] = s;
  }
  float sqr[4];
  #pragma unroll
  for (int rg=0;rg<4;++rg) sqr[rg] = sq[rloc + rg];

  // stage output tile [64][256] into LDS (overlays sP; all sP/sA/sq reads
  // complete for every wave after this barrier)
  __syncthreads();
  u16* sOut = sP;
  const int xorW = (lane>>4) << 2;   // == ((row>>2)&3)<<2 for this thread's rows
  #pragma unroll
  for (int nt=0;nt<16;++nt){
    int gcol = nt*2 + ((lane&15)>>3);
    int gS = (gcol ^ xorW)*8 + (lane&7);
    #pragma unroll
    for (int rg=0;rg<4;++rg){
      float val = (__expf(fminf(acc[nt][rg] - sqr[rg] - stab[rg], 0.f)) + EPSF) * 0.0625f;
      sOut[(rloc + rg)*256 + gS] = f2u(val);
    }
  }
  __syncthreads();
  // coalesced store: 2048 short8 / 256 threads = 8 each
  #pragma unroll
  for (int j=0;j<8;++j){
    int idx = tid + j*256;         // 0..2047
    int r = idx >> 5, g = idx & 31;
    short8 v = *(const short8*)&sOut[r*256 + (g ^ (((r>>2)&3)<<2))*8];
    *(short8*)&phi[(row0 + r)*MFEAT + g*8] = v;
  }
}

__global__ void stab_reduce_kernel(const float* __restrict__ rmaxk, float* __restrict__ stabk){
  __shared__ float red[256];
  int bk = blockIdx.x;
  float mx = -1e30f;
  for (int i = threadIdx.x; i < SEQ; i += 256) mx = fmaxf(mx, rmaxk[(size_t)bk*SEQ + i]);
  red[threadIdx.x] = mx; __syncthreads();
  for (int off=128; off>0; off>>=1){
    if ((int)threadIdx.x < off) red[threadIdx.x] = fmaxf(red[threadIdx.x], red[threadIdx.x+off]);
    __syncthreads();
  }
  if (threadIdx.x==0) stabk[bk] = red[0];
}

// ---------------------------------------------------------------------------
// V transpose: vbuf fp32 [bk][s][d] -> vT bf16 [bk][d][s].  256 blocks.
// ---------------------------------------------------------------------------
__global__ __launch_bounds__(256) void vtrans_kernel(const float* __restrict__ vbuf,
                                                     u16* __restrict__ vT)
{
  int blk = blockIdx.x;          // 16 bk x 16 sc
  int bk = blk >> 4, sc = blk & 15;
  const float* src = vbuf + ((size_t)bk*SEQ + sc*128)*DH;
  __shared__ float sT[128*65];
  for (int i=0;i<32;++i){ int idx = threadIdx.x + i*256; sT[(idx>>6)*65 + (idx&63)] = src[idx]; }
  __syncthreads();
  #pragma unroll
  for (int i=0;i<4;++i){
    int gi = threadIdx.x + i*256;  // 0..1023
    int d = gi >> 4, t8 = (gi & 15)*8;
    u16 tmp[8];
    #pragma unroll
    for (int j=0;j<8;++j) tmp[j] = f2u(sT[(t8+j)*65 + d]);
    *(short8*)&vT[((size_t)bk*DH + d)*SEQ + sc*128 + t8] = *(const short8*)tmp;
  }
}

// ---------------------------------------------------------------------------
// kv/kz per-chunk sums: block = (bk, c); thread m accumulates phik[t,m]*v[t,:]
// kv written TRANSPOSED [blk][d][m] (coalesced: lanes share d, consecutive m).
// ---------------------------------------------------------------------------
__global__ __launch_bounds__(256) void kvchunk_kernel(const bf16* __restrict__ phik,
    const float* __restrict__ vbuf, float* __restrict__ kv, float* __restrict__ kz)
{
  int blk = blockIdx.x; int bk = blk >> 4, c = blk & 15;
  const bf16* Kc = phik + ((size_t)bk*SEQ + c*128)*MFEAT;
  const float* Vc = vbuf + ((size_t)bk*SEQ + c*128)*DH;
  __shared__ float sV[128*64];
  for (int l=0;l<32;++l){ int idx = threadIdx.x + l*256; sV[idx] = Vc[idx]; }
  __syncthreads();
  int m = threadIdx.x;
  float acc[64] = {}; float az = 0.f;
  for (int t=0;t<128;++t){
    float ph = b2f(Kc[(size_t)t*MFEAT + m]);
    az += ph;
    const float4* vr = (const float4*)&sV[t*64];
    #pragma unroll
    for (int d4=0; d4<16; ++d4){
      float4 v4 = vr[d4];
      acc[d4*4+0] += ph*v4.x; acc[d4*4+1] += ph*v4.y;
      acc[d4*4+2] += ph*v4.z; acc[d4*4+3] += ph*v4.w;
    }
  }
  float* out = kv + (size_t)blk*MFEAT*DH;
  #pragma unroll
  for (int d=0; d<64; ++d) out[(size_t)d*MFEAT + m] = acc[d];
  kz[(size_t)blk*MFEAT + m] = az;
}

// exclusive prefix over chunk axis; writes bf16 prefix to ob (fp32 p unchanged)
__global__ void scan_kernel(float* __restrict__ p, u16* __restrict__ ob,
                            int inner, int nc, int total){
  int t = blockIdx.x*256 + threadIdx.x;
  if (t >= total) return;
  int outer = t / inner, rem = t - outer*inner;
  const float* base = p + (size_t)outer*nc*inner + rem;
  u16* obase = ob + (size_t)outer*nc*inner + rem;
  float run = 0.f;
  for (int c=0;c<nc;++c){
    float v = base[(size_t)c*inner];
    obase[(size_t)c*inner] = f2u(run);
    run += v;
  }
}

// ---------------------------------------------------------------------------
// MFMA attention: block = (b,h,chunk). 4 waves, each owns 32 rows.
// BLOCK ORDER (L2 reuse): logical lb = ((b*8+kvh)*16+c)*4+hh — the 4 heads
// sharing one KV group are adjacent, one (b,kvh) = 64 contiguous blocks;
// XCD chunking (lb = (bix&7)*128 + bix>>3) keeps sharers on one XCD's L2.
// P1/P3 fused over feat chunks of 32: S += Q*K^T, O += Q*[KVpre|KZpre]
// K0-loop double-buffered; all staging async (cp16) from bf16 sources.
// mask S in regs -> P to LDS (bf16, stride 136); P2: O += P*[V|1]^T.
// z (col 64) = ez+iz -> divide -> store (b,s,h,d) bf16.
// ---------------------------------------------------------------------------
__global__ __launch_bounds__(256) void attn_mfma(
    const u16* __restrict__ phiq, const u16* __restrict__ phik,
    const u16* __restrict__ kvpb, const u16* __restrict__ kzpb,
    const u16* __restrict__ vT, u16* __restrict__ attnout)
{
  __shared__ __align__(16) u16 smem[31232];
  __shared__ float sZ[128];
  const int tid = threadIdx.x, lane = tid & 63, wave = tid >> 6;
  // XCD-chunked, KV-sharers-adjacent block decode (1024 blocks, %8==0)
  int lb = (blockIdx.x & 7) * 128 + (blockIdx.x >> 3);
  const int hh = lb & 3, c = (lb >> 2) & 15, kvh = (lb >> 6) & 7, b = lb >> 9;
  const int h = kvh*4 + hh;
  const int bkv = b*NKVH + kvh;
  const u16* Q   = phiq + (((size_t)(b*NHEAD+h)*SEQ) + c*128)*MFEAT;
  const u16* Kc  = phik + (((size_t)bkv*SEQ) + c*128)*MFEAT;
  const u16* KVb = kvpb + ((size_t)(bkv*NCH + c))*MFEAT*DH;   // [d][m] bf16
  const u16* KZb = kzpb + ((size_t)(bkv*NCH + c))*MFEAT;
  const u16* vTb = vT + (size_t)bkv*DH*SEQ;                    // [d][s] bf16

  u16* sQb[2]  = { smem,         smem + 4096 };
  u16* sKb[2]  = { smem + 8192,  smem + 12288 };
  u16* sKVb[2] = { smem + 16384, smem + 18560 };
  u16* sVT = smem + 20736;
  u16* sP  = smem;

  f32x4 accS[2][8] = {};
  f32x4 accO[2][5] = {};

  const int ch0 = wave*64 + lane, ch1 = 256 + wave*64 + lane;
  const u16* gQ0 = Q  + (ch0>>2)*MFEAT + (ch0&3)*8;
  const u16* gQ1 = Q  + (ch1>>2)*MFEAT + (ch1&3)*8;
  const u16* gK0 = Kc + (ch0>>2)*MFEAT + (ch0&3)*8;
  const u16* gK1 = Kc + (ch1>>2)*MFEAT + (ch1&3)*8;

  const int dKV = wave*16 + (lane>>2);
  const u16* gKVsrc = KVb + (size_t)dKV*MFEAT + (((lane&3) ^ (dKV&3))<<3);

  #define ASTAGE(bi, kk) do {                                      \
    cp16(sQb[bi] + wave*512,        gQ0 + (kk));                   \
    cp16(sQb[bi] + 2048 + wave*512, gQ1 + (kk));                   \
    cp16(sKb[bi] + wave*512,        gK0 + (kk));                   \
    cp16(sKb[bi] + 2048 + wave*512, gK1 + (kk));                   \
    cp16(sKVb[bi] + wave*512,       gKVsrc + (kk));                \
    if (tid < 4) cp16(sKVb[bi] + 2048, KZb + (kk) + tid*8);        \
  } while(0)

  ASTAGE(0, 0);
  #pragma unroll
  for (int i=0;i<4;++i){
    int gi = tid + i*256;          // 0..1023
    int d  = gi >> 4, g = gi & 15;
    cp16(&sVT[(i*256 + wave*64)*8],
         vTb + (size_t)d*SEQ + c*128 + ((g ^ (d&7))<<3));
  }
  asm volatile("s_waitcnt vmcnt(4)" ::: "memory");
  SBAR();

  #pragma unroll
  for (int t = 0; t < 8; ++t) {
    const int bi = t & 1;
    if (t < 7) ASTAGE(bi^1, (t+1)*32);

    short8 af0, af1;
    const u16* pQ = &sQb[bi][(wave*32 + (lane&15))*32 + (lane>>4)*8];
    af0 = *(const short8*)(pQ);
    af1 = *(const short8*)(pQ + 512);
    #pragma unroll
    for (int nt=0;nt<8;++nt){
      short8 bk = *(const short8*)&sKb[bi][(nt*16 + (lane&15))*32 + (lane>>4)*8];
      accS[0][nt] = MFMA16(af0, bk, accS[0][nt]);
      accS[1][nt] = MFMA16(af1, bk, accS[1][nt]);
    }
    #pragma unroll
    for (int nt=0;nt<5;++nt){
      int row = nt*16 + (lane&15);
      short8 bi8 = *(const short8*)&sKVb[bi][row*32 + (((lane>>4) ^ (row&3))<<3)];
      accO[0][nt] = MFMA16(af0, bi8, accO[0][nt]);
      accO[1][nt] = MFMA16(af1, bi8, accO[1][nt]);
    }
    asm volatile("s_waitcnt vmcnt(0)" ::: "memory");
    SBAR();
  }
  #undef ASTAGE

  // mask + write P (bf16, stride 136); ones row for sVT
  #pragma unroll
  for (int mt=0;mt<2;++mt){
    int rowb = wave*32 + mt*16 + (lane>>4)*4;
    #pragma unroll
    for (int nt=0;nt<8;++nt){
      int col = nt*16 + (lane&15);
      #pragma unroll
      for (int rg=0;rg<4;++rg){
        int row = rowb + rg;
        float v = (col <= row) ? accS[mt][nt][rg] : 0.f;
        sP[row*136 + col] = f2u(v);
      }
    }
  }
  if (tid < 16){
    u16 ones[8] = {0x3F80,0x3F80,0x3F80,0x3F80,0x3F80,0x3F80,0x3F80,0x3F80};
    *(short8*)&sVT[64*128 + tid*8] = *(const short8*)ones;
  }
  __syncthreads();

  // P2: O += P @ [V|1]  (sVT granule-swizzled read)
  #pragma unroll
  for (int kc=0;kc<4;++kc){
    const u16* pP = &sP[(wave*32 + (lane&15))*136 + kc*32 + (lane>>4)*8];
    short8 pa0 = *(const short8*)(pP);
    short8 pa1 = *(const short8*)(pP + 16*136);
    #pragma unroll
    for (int nt=0;nt<5;++nt){
      int row = nt*16 + (lane&15);
      int g   = kc*4 + (lane>>4);
      short8 bv = *(const short8*)&sVT[row*128 + ((g ^ (row&7))<<3)];
      accO[0][nt] = MFMA16(pa0, bv, accO[0][nt]);
      accO[1][nt] = MFMA16(pa1, bv, accO[1][nt]);
    }
  }

  // z broadcast + divide + store
  if ((lane & 15) == 0){
    #pragma unroll
    for (int mt=0;mt<2;++mt){
      int rowb = wave*32 + mt*16 + (lane>>4)*4;
      #pragma unroll
      for (int rg=0;rg<4;++rg) sZ[rowb + rg] = accO[mt][4][rg];
    }
  }
  __syncthreads();
  const int d0 = lane & 15;
  #pragma unroll
  for (int mt=0;mt<2;++mt){
    int rowb = wave*32 + mt*16 + (lane>>4)*4;
    #pragma unroll
    for (int rg=0;rg<4;++rg){
      int row = rowb + rg;
      float inv = 1.0f / (sZ[row] + EPSF);
      int sg = c*128 + row;
      size_t ob = (((size_t)b*SEQ + sg)*NHEAD + h)*DH;
      #pragma unroll
      for (int nt=0;nt<4;++nt)
        attnout[ob + nt*16 + d0] = f2u(accO[mt][nt][rg] * inv);
    }
  }
}

// ---------------------------------------------------------------------------
extern "C" void kernel_launch(void* const* d_in, const int* in_sizes, int n_in,
                              void* d_out, int out_size, void* d_ws, size_t ws_size,
                              hipStream_t stream)
{
  const void* hidden = d_in[0];
  const void* cosg   = d_in[1];
  const void* sing   = d_in[2];
  const void* Wq     = d_in[3];
  const void* Wk     = d_in[4];
  const void* Wv     = d_in[5];
  const void* Wo     = d_in[6];
  const void* proj   = d_in[7];
  const unsigned* probe = (const unsigned*)d_in[1];

  float* ws = (float*)d_ws;
  // overlays (stream-order safe):
  //   [0, 8388608): xnq (until phi_mfma q); then kv/kz/rmaxk/stabk/vT/kvpb/kzpb
  float* xnq   = ws;                       // 8388608 f
  float* kv    = ws;                       // 4194304 f (after phi q)
  float* kz    = ws + 4194304;             //   65536 f
  float* rmaxk = ws + 4259840;             //   32768 f
  float* stabk = ws + 4292608;             //     256 f
  u16*   vT    = (u16*) (ws + 4292864);    //  2097152 u16 (after phi q)
  u16*   kvpb  = (u16*) (ws + 5341440);    //  4194304 u16
  u16*   kzpb  = (u16*) (ws + 7438592);    //    65536 u16
  float* xnk   = ws + 8388608;             // 2097152 f
  float* vbuf  = ws + 10485760;            // 2097152 f
  u16*   projb = (u16*) (ws + 12582912);   //   16384 bf16
  bf16*  phiq  = (bf16*)(ws + 12591104);   // 33554432 bf16
  bf16*  phik  = (bf16*)(ws + 29368320);   //  8388608 bf16
  u16*   hb    = (u16*) (ws + 33562624);   //  8388608 bf16 (hidden; attn later)
  u16*   attn  = (u16*) (ws + 33562624);   //  (same region, after QKV gemm)
  u16*   wqkv  = (u16*) (ws + 37756928);   //  6291456 bf16
  u16*   wob   = (u16*) (ws + 37756928);   //  (same region, after QKV gemm)

  // converts (vectorized): hidden, fused Wq|Wk|Wv, proj
  conv_kernel<<<4096, 256, 0, stream>>>(hidden, hb, probe);
  wconv_kernel<<<3072, 256, 0, stream>>>(Wq, Wk, Wv, wqkv, probe);
  conv_kernel<<<8,    256, 0, stream>>>(proj, projb, probe);

  // fused QKV projection + RoPE + dn (fp32 head-major out); 256x128 tiles
  gemm_mfma<<<dim3(24,16), 512, 0, stream>>>(hb, wqkv, xnq, xnk, vbuf, nullptr,
                                             2048, 3072, 1, cosg, sing, probe);
  // Wo convert (reuses wqkv region; ordered after QKV gemm)
  conv_kernel<<<2048, 256, 0, stream>>>(Wo, wob, probe);

  // phi features via MFMA
  phi_mfma<<<2048, 256, 0, stream>>>(xnq, projb, nullptr, nullptr, (u16*)phiq, 0);
  // V transpose to bf16 (xnq dead now; vT overlays its tail region)
  vtrans_kernel<<<256, 256, 0, stream>>>(vbuf, vT);
  phi_mfma<<<512,  256, 0, stream>>>(xnk, projb, rmaxk, nullptr, nullptr, 1);
  stab_reduce_kernel<<<16, 256, 0, stream>>>(rmaxk, stabk);
  phi_mfma<<<512,  256, 0, stream>>>(xnk, projb, nullptr, stabk, (u16*)phik, 2);

  // chunk kv/kz states (kv transposed [blk][d][m]) + exclusive prefix -> bf16
  kvchunk_kernel<<<256, 256, 0, stream>>>(phik, vbuf, kv, kz);
  scan_kernel<<<1024, 256, 0, stream>>>(kv, kvpb, MFEAT*DH, NCH, 16*MFEAT*DH);
  scan_kernel<<<16,   256, 0, stream>>>(kz, kzpb, MFEAT,    NCH, 16*MFEAT);

  // MFMA attention (all-bf16 async staging, KV-sharing block order)
  attn_mfma<<<1024, 256, 0, stream>>>((const u16*)phiq, (const u16*)phik,
                                      kvpb, kzpb, vT, attn);

  // output projection (out dtype follows input dtype); 256x128 tiles
  gemm_mfma<<<dim3(16,16), 512, 0, stream>>>(attn, wob, nullptr, nullptr, nullptr,
                                             d_out, 2048, 2048, 0, nullptr, nullptr, probe);
}

// Round 9
// 429.194 us; speedup vs baseline: 1.0604x; 1.0604x over previous
//
#include <hip/hip_runtime.h>
#include <hip/hip_bf16.h>

// Problem constants (B=2, S=2048, HID=2048, NH=32, NKV=8, D=64, M=256, CHUNK=128)
#define SEQ   2048
#define NHEAD 32
#define NKVH  8
#define DH    64
#define MFEAT 256
#define NCH   16
#define EPSF  1e-6f

typedef __hip_bfloat16 bf16;
typedef unsigned short u16;
typedef __attribute__((ext_vector_type(8))) short short8;   // 8 bf16 (4 VGPRs)
typedef __attribute__((ext_vector_type(4))) float f32x4;    // 4 fp32 acc

__device__ __forceinline__ float b2f(bf16 x){ return __bfloat162float(x); }
__device__ __forceinline__ bf16  f2b(float x){ return __float2bfloat16(x); }
__device__ __forceinline__ u16   f2u(float x){ bf16 h = __float2bfloat16(x); return *reinterpret_cast<u16*>(&h); }

// dtype probe: d_in[1] is cos; cos[0]==1.0 exactly.
// fp32 -> word0 = 0x3F800000 (low16==0). bf16-packed -> low16!=0.
__device__ __forceinline__ bool probe_f32(const unsigned* __restrict__ p){
  return (p[0] & 0xFFFFu) == 0u;
}
__device__ __forceinline__ float loadIn(const void* __restrict__ ptr, size_t idx, bool f32){
  return f32 ? ((const float*)ptr)[idx] : b2f(((const bf16*)ptr)[idx]);
}

// async 16B global -> LDS (wave-uniform LDS base; HW adds lane*16)
__device__ __forceinline__ void cp16(u16* lds, const u16* g){
  __builtin_amdgcn_global_load_lds((const __attribute__((address_space(1))) unsigned*)g,
      (__attribute__((address_space(3))) unsigned*)lds, 16, 0, 0);
}

#define MFMA16(a,b,c) __builtin_amdgcn_mfma_f32_16x16x32_bf16(a,b,c,0,0,0)
#define SBAR()  do { __builtin_amdgcn_s_barrier(); __builtin_amdgcn_sched_barrier(0); } while(0)

// ---------------------------------------------------------------------------
// dtype convert: src (fp32 or bf16 per probe) -> bf16 (u16) dst.
// Vectorized: 8 elems/thread (f32: 2x float4 -> short8; bf16: short8 copy).
// ---------------------------------------------------------------------------
__device__ __forceinline__ void conv8(const void* __restrict__ src, size_t i8,
                                      u16* __restrict__ dst, size_t o8, bool f32in)
{
  if (f32in){
    const float4* s = (const float4*)src;
    float4 a = s[i8*2], b = s[i8*2+1];
    u16 t[8] = {f2u(a.x),f2u(a.y),f2u(a.z),f2u(a.w),
                f2u(b.x),f2u(b.y),f2u(b.z),f2u(b.w)};
    *(short8*)&dst[o8*8] = *(const short8*)t;
  } else {
    *(short8*)&dst[o8*8] = ((const short8*)src)[i8];
  }
}

__global__ __launch_bounds__(256) void conv_kernel(const void* __restrict__ src,
    u16* __restrict__ dst, const unsigned* __restrict__ probe)
{
  const bool f32in = probe_f32(probe);
  size_t i = (size_t)blockIdx.x*256 + threadIdx.x;
  conv8(src, i, dst, i, f32in);
}

// fused Wq|Wk|Wv convert -> contiguous wqkv (8-elem units: 524288|131072|131072)
__global__ __launch_bounds__(256) void wconv_kernel(const void* __restrict__ Wq,
    const void* __restrict__ Wk, const void* __restrict__ Wv,
    u16* __restrict__ dst, const unsigned* __restrict__ probe)
{
  const bool f32in = probe_f32(probe);
  size_t i = (size_t)blockIdx.x*256 + threadIdx.x;
  const void* src; size_t off;
  if (i < 524288){ src = Wq; off = i; }
  else if (i < 655360){ src = Wk; off = i - 524288; }
  else { src = Wv; off = i - 655360; }
  conv8(src, off, dst, i, f32in);
}

// ---------------------------------------------------------------------------
// MFMA GEMM (round-3 structure, best measured): C[r,c] = sum_k A[r,k]*W[c,k];
// A,W row-major bf16 (u16).  Tile 256x128, BK=64, 8 waves (4M x 2N ->
// per-wave 64x64, acc[4][4]).  3-slot pipeline, counted s_waitcnt vmcnt(6)
// once per K-tile (never 0 until last tile).  K-tile body in 4 phases:
//   phase p: { ds_read quad frags | 2 stage cp16 } -> barrier ->
//            setprio(1) -> 8 MFMA -> setprio(0) -> barrier
// T2 LDS XOR-swizzle (col ^= (row&7)<<3) via pre-swizzled global source +
// swizzled ds_read.  XCD-aware block swizzle.
// mode 0: outAny[r*N+c] (dtype probed f32/bf16)
// mode 1: qkv scatter -> oq/ok/ov fp32 head-major [b,h,s,d], RoPE+dn fused
//         for q,k (each wave's 64-col span is one head; d^32 partner = nt^2).
// ---------------------------------------------------------------------------
__global__ __launch_bounds__(512) void gemm_mfma(const u16* __restrict__ A,
    const u16* __restrict__ W, float* __restrict__ oq, float* __restrict__ ok,
    float* __restrict__ ov, void* __restrict__ outAny, int K, int N, int mode,
    const void* __restrict__ cosg, const void* __restrict__ sing,
    const unsigned* __restrict__ probe)
{
  __shared__ __align__(16) u16 sA[3][16384];   // 3 x 256x64
  __shared__ __align__(16) u16 sB[3][8192];    // 3 x 128x64
  const int tid = threadIdx.x;
  const int lane = tid & 63, wave = tid >> 6;

  // XCD-aware swizzle: contiguous chunk of logical tiles per XCD.
  const int nbx = gridDim.x;
  const int nwg = nbx * gridDim.y;
  int id = blockIdx.y * nbx + blockIdx.x;
  int sw = id;
  if ((nwg & 7) == 0) sw = (id & 7) * (nwg >> 3) + (id >> 3);
  const int bx = sw % nbx, by = sw / nbx;
  const int c0 = bx*128, r0 = by*256;

  const int wm = wave >> 1, wn = wave & 1;
  f32x4 acc[4][4] = {};

  // --- staging: 6 x cp16 per thread per K-tile (A:4, B:2), pre-swizzled src.
  const int rl  = lane >> 3;
  const int swzE = ((lane & 7) ^ rl) << 3;
  const u16* gA = A + (size_t)(r0 + wave*8 + rl)*K + swzE;
  const u16* gB = W + (size_t)(c0 + wave*8 + rl)*K + swzE;
  const int aDst = wave*512;   // u16 offset in buf; +i*4096 per 64-row group
  const int bDst = wave*512;

  // --- frag ds_read offsets (u16): row*64 + (col ^ ((row&7)<<3)); row&7==lane&7
  const int rowA = (wm*64 + (lane&15))*64;
  const int rowB = (wn*64 + (lane&15))*64;
  const int colS = (((lane>>4)*8) ^ ((lane&7)<<3));   // ks=0 ; ks=1 -> ^32

  const int nk = K >> 6;   // K=2048 -> 32 K-tiles

  #define STAGE_ALL(buf, t) do { const int k0_ = (t)*64;                  \
    cp16(&sA[buf][aDst],         gA + k0_);                               \
    cp16(&sA[buf][aDst + 4096],  gA + (size_t)64*K  + k0_);               \
    cp16(&sA[buf][aDst + 8192],  gA + (size_t)128*K + k0_);               \
    cp16(&sA[buf][aDst + 12288], gA + (size_t)192*K + k0_);               \
    cp16(&sB[buf][bDst],         gB + k0_);                               \
    cp16(&sB[buf][bDst + 4096],  gB + (size_t)64*K  + k0_); } while(0)

  // prologue: tiles 0,1 in flight (12 loads)
  STAGE_ALL(0, 0);
  STAGE_ALL(1, 1);

  int cur = 0;
  for (int t = 0; t < nk; ++t) {
    // own tile-t loads retired (newest 6 = tile t+1 stay in flight);
    // barrier makes that true for ALL waves' tile-t loads.
    if (t < nk-1) asm volatile("s_waitcnt vmcnt(6)" ::: "memory");
    else          asm volatile("s_waitcnt vmcnt(0)" ::: "memory");
    SBAR();

    int sb = cur + 2; if (sb >= 3) sb -= 3;
    const int k0s = (t + 2) * 64;
    const bool st = (t + 2 < nk);
    const u16* bA_ = sA[cur];
    const u16* bB_ = sB[cur];

    short8 a01[2][2], a23[2][2], b01[2][2], b23[2][2];

    // ---- phase 0: read A01+B01 ; stage A groups 0,1 ; MFMA mt01 x nt01
    #pragma unroll
    for (int mt=0;mt<2;++mt){
      a01[mt][0] = *(const short8*)(bA_ + rowA + mt*1024 + colS);
      a01[mt][1] = *(const short8*)(bA_ + rowA + mt*1024 + (colS^32));
    }
    #pragma unroll
    for (int nt=0;nt<2;++nt){
      b01[nt][0] = *(const short8*)(bB_ + rowB + nt*1024 + colS);
      b01[nt][1] = *(const short8*)(bB_ + rowB + nt*1024 + (colS^32));
    }
    if (st){ cp16(&sA[sb][aDst], gA + k0s);
             cp16(&sA[sb][aDst + 4096], gA + (size_t)64*K + k0s); }
    SBAR();
    __builtin_amdgcn_s_setprio(1);
    #pragma unroll
    for (int mt=0;mt<2;++mt)
      #pragma unroll
      for (int nt=0;nt<2;++nt){
        acc[mt][nt] = MFMA16(a01[mt][0], b01[nt][0], acc[mt][nt]);
        acc[mt][nt] = MFMA16(a01[mt][1], b01[nt][1], acc[mt][nt]);
      }
    __builtin_amdgcn_s_setprio(0);
    SBAR();

    // ---- phase 1: read B23 ; stage A groups 2,3 ; MFMA mt01 x nt23
    #pragma unroll
    for (int nt=0;nt<2;++nt){
      b23[nt][0] = *(const short8*)(bB_ + rowB + (nt+2)*1024 + colS);
      b23[nt][1] = *(const short8*)(bB_ + rowB + (nt+2)*1024 + (colS^32));
    }
    if (st){ cp16(&sA[sb][aDst + 8192],  gA + (size_t)128*K + k0s);
             cp16(&sA[sb][aDst + 12288], gA + (size_t)192*K + k0s); }
    SBAR();
    __builtin_amdgcn_s_setprio(1);
    #pragma unroll
    for (int mt=0;mt<2;++mt)
      #pragma unroll
      for (int nt=0;nt<2;++nt){
        acc[mt][nt+2] = MFMA16(a01[mt][0], b23[nt][0], acc[mt][nt+2]);
        acc[mt][nt+2] = MFMA16(a01[mt][1], b23[nt][1], acc[mt][nt+2]);
      }
    __builtin_amdgcn_s_setprio(0);
    SBAR();

    // ---- phase 2: read A23 ; stage B groups 0,1 ; MFMA mt23 x nt23
    #pragma unroll
    for (int mt=0;mt<2;++mt){
      a23[mt][0] = *(const short8*)(bA_ + rowA + (mt+2)*1024 + colS);
      a23[mt][1] = *(const short8*)(bA_ + rowA + (mt+2)*1024 + (colS^32));
    }
    if (st){ cp16(&sB[sb][bDst], gB + k0s);
             cp16(&sB[sb][bDst + 4096], gB + (size_t)64*K + k0s); }
    SBAR();
    __builtin_amdgcn_s_setprio(1);
    #pragma unroll
    for (int mt=0;mt<2;++mt)
      #pragma unroll
      for (int nt=0;nt<2;++nt){
        acc[mt+2][nt+2] = MFMA16(a23[mt][0], b23[nt][0], acc[mt+2][nt+2]);
        acc[mt+2][nt+2] = MFMA16(a23[mt][1], b23[nt][1], acc[mt+2][nt+2]);
      }
    __builtin_amdgcn_s_setprio(0);
    SBAR();

    // ---- phase 3: no reads/stages ; MFMA mt23 x nt01 (reuse a23, b01)
    __builtin_amdgcn_s_setprio(1);
    #pragma unroll
    for (int mt=0;mt<2;++mt)
      #pragma unroll
      for (int nt=0;nt<2;++nt){
        acc[mt+2][nt] = MFMA16(a23[mt][0], b01[nt][0], acc[mt+2][nt]);
        acc[mt+2][nt] = MFMA16(a23[mt][1], b01[nt][1], acc[mt+2][nt]);
      }
    __builtin_amdgcn_s_setprio(0);
    // phase-3 end barrier = next iteration's top barrier

    cur = (cur == 2) ? 0 : cur + 1;
  }
  #undef STAGE_ALL

  const int rbase = r0 + wm*64 + (lane>>4)*4;   // + mt*16 + rg
  const int cbase = c0 + wn*64 + (lane&15);     // + nt*16
  if (mode == 0) {
    const bool f32o = probe_f32(probe);
    #pragma unroll
    for (int mt=0;mt<4;++mt)
      #pragma unroll
      for (int nt=0;nt<4;++nt)
        #pragma unroll
        for (int rg=0;rg<4;++rg){
          int r = rbase + mt*16 + rg, c = cbase + nt*16;
          float v = acc[mt][nt][rg];
          if (f32o) ((float*)outAny)[(size_t)r*N + c] = v;
          else      ((u16*)outAny)[(size_t)r*N + c] = f2u(v);
        }
  } else {
    const bool f32in = probe_f32(probe);
    const float dn = 0.3535533905932738f;  // 64^-0.25
    #pragma unroll
    for (int nt=0;nt<4;++nt){
      int cc = cbase + nt*16;
      float* dst; int H2, cl; bool isv = false;
      if (cc < 2048){ dst = oq; H2 = 32; cl = cc; }
      else if (cc < 2560){ dst = ok; H2 = 8; cl = cc - 2048; }
      else { dst = ov; H2 = 8; cl = cc - 2560; isv = true; }
      int hh = cl>>6, dd = cl&63;
      float sgn = (dd < 32) ? -1.f : 1.f;
      #pragma unroll
      for (int mt=0;mt<4;++mt)
        #pragma unroll
        for (int rg=0;rg<4;++rg){
          int r = rbase + mt*16 + rg;
          int bb = r>>11, s = r&2047;
          float v = acc[mt][nt][rg];
          if (!isv){
            float vp = acc[mt][nt^2][rg];
            size_t ci = ((size_t)bb*SEQ + s)*DH + dd;
            float cv = loadIn(cosg, ci, f32in);
            float sv = loadIn(sing, ci, f32in);
            v = (v*cv + sgn*vp*sv) * dn;
          }
          dst[(((size_t)bb*H2 + hh)*SEQ + s)*DH + dd] = v;
        }
    }
  }
}

// ---------------------------------------------------------------------------
// phi via MFMA: xp = xn[rows x 64] @ proj[256 x 64]^T, K=64.
// 64 rows/block, 4 waves x (1 row-tile x 16 col-tiles).
// mode 0: q — rowwise stab, exp, write phi
// mode 1: k pass A — rowwise max -> rmaxk
// mode 2: k pass B — exp with global stabk, write phi
// ---------------------------------------------------------------------------
__global__ __launch_bounds__(256) void phi_mfma(const float* __restrict__ xn,
    const u16* __restrict__ projb, float* __restrict__ rmaxk,
    const float* __restrict__ stabk, u16* __restrict__ phi, int mode)
{
  __shared__ __align__(16) u16 sA[64*80];
  __shared__ __align__(16) u16 sP[256*80];
  __shared__ float sq[64];
  const int tid = threadIdx.x, lane = tid & 63, wave = tid >> 6;
  const size_t row0 = (size_t)blockIdx.x * 64;

  // stage proj: 2048 short8 vectors -> [m][80] padded
  #pragma unroll
  for (int l = 0; l < 8; ++l){
    int v8 = tid + l*256;
    int off = v8*8; int m = off>>6, d = off&63;
    *(short8*)&sP[m*80 + d] = ((const short8*)projb)[v8];
  }
  // stage xn rows fp32 -> bf16 + sq partials (thread = row tid>>2, quarter tid&3)
  {
    int r = tid >> 2, qq = tid & 3;
    const float* src = xn + (row0 + r)*DH + qq*16;
    float s = 0.f;
    u16 tmp[16];
    #pragma unroll
    for (int i=0;i<16;i+=4){
      float4 v4 = *(const float4*)&src[i];
      s += v4.x*v4.x + v4.y*v4.y + v4.z*v4.z + v4.w*v4.w;
      tmp[i] = f2u(v4.x); tmp[i+1] = f2u(v4.y); tmp[i+2] = f2u(v4.z); tmp[i+3] = f2u(v4.w);
    }
    *(short8*)&sA[r*80 + qq*16]     = *(short8*)&tmp[0];
    *(short8*)&sA[r*80 + qq*16 + 8] = *(short8*)&tmp[8];
    s += __shfl_xor(s, 1, 64);
    s += __shfl_xor(s, 2, 64);
    if (qq == 0) sq[r] = 0.5f*s;
  }
  __syncthreads();

  // MFMA: wave owns rows wave*16..+15; 16 col-tiles, 2 k-steps
  f32x4 acc[16] = {};
  const u16* pA = &sA[(wave*16 + (lane&15))*80 + (lane>>4)*8];
  short8 af0 = *(const short8*)(pA);
  short8 af1 = *(const short8*)(pA + 32);
  #pragma unroll
  for (int nt=0; nt<16; ++nt){
    const u16* pB = &sP[(nt*16 + (lane&15))*80 + (lane>>4)*8];
    short8 b0 = *(const short8*)(pB);
    short8 b1 = *(const short8*)(pB + 32);
    acc[nt] = MFMA16(af0, b0, acc[nt]);
    acc[nt] = MFMA16(af1, b1, acc[nt]);
  }

  // rowwise max across 256 cols (in-reg over nt, then 16-lane butterfly)
  float mx[4];
  #pragma unroll
  for (int rg=0; rg<4; ++rg){
    float m = acc[0][rg];
    #pragma unroll
    for (int nt=1; nt<16; ++nt) m = fmaxf(m, acc[nt][rg]);
    m = fmaxf(m, __shfl_xor(m, 1, 64));
    m = fmaxf(m, __shfl_xor(m, 2, 64));
    m = fmaxf(m, __shfl_xor(m, 4, 64));
    m = fmaxf(m, __shfl_xor(m, 8, 64));
    mx[rg] = m;
  }
  const int rloc = wave*16 + (lane>>4)*4;   // + rg
  if (mode == 1){
    if ((lane & 15) == 0){
      #pragma unroll
      for (int rg=0;rg<4;++rg) rmaxk[row0 + rloc + rg] = mx[rg];
    }
    return;
  }
  float stab[4];
  if (mode == 0){
    #pragma unroll
    for (int rg=0;rg<4;++rg) stab[rg] = mx[rg];
  } else {
    float s = stabk[row0 >> 11];
    #pragma unroll
    for (int rg=0;rg<4;++rg) stab[rg] = s;
  }
  float sqr[4];
  #pragma unroll
  for (int rg=0;rg<4;++rg) sqr[rg] = sq[rloc + rg];
  #pragma unroll
  for (int nt=0;nt<16;++nt){
    #pragma unroll
    for (int rg=0;rg<4;++rg){
      float val = (__expf(fminf(acc[nt][rg] - sqr[rg] - stab[rg], 0.f)) + EPSF) * 0.0625f;
      phi[(row0 + rloc + rg)*MFEAT + nt*16 + (lane&15)] = f2u(val);
    }
  }
}

__global__ void stab_reduce_kernel(const float* __restrict__ rmaxk, float* __restrict__ stabk){
  __shared__ float red[256];
  int bk = blockIdx.x;
  float mx = -1e30f;
  for (int i = threadIdx.x; i < SEQ; i += 256) mx = fmaxf(mx, rmaxk[(size_t)bk*SEQ + i]);
  red[threadIdx.x] = mx; __syncthreads();
  for (int off=128; off>0; off>>=1){
    if ((int)threadIdx.x < off) red[threadIdx.x] = fmaxf(red[threadIdx.x], red[threadIdx.x+off]);
    __syncthreads();
  }
  if (threadIdx.x==0) stabk[bk] = red[0];
}

// ---------------------------------------------------------------------------
// V transpose: vbuf fp32 [bk][s][d] -> vT bf16 [bk][d][s].  256 blocks.
// ---------------------------------------------------------------------------
__global__ __launch_bounds__(256) void vtrans_kernel(const float* __restrict__ vbuf,
                                                     u16* __restrict__ vT)
{
  int blk = blockIdx.x;          // 16 bk x 16 sc
  int bk = blk >> 4, sc = blk & 15;
  const float* src = vbuf + ((size_t)bk*SEQ + sc*128)*DH;
  __shared__ float sT[128*65];
  for (int i=0;i<32;++i){ int idx = threadIdx.x + i*256; sT[(idx>>6)*65 + (idx&63)] = src[idx]; }
  __syncthreads();
  #pragma unroll
  for (int i=0;i<4;++i){
    int gi = threadIdx.x + i*256;  // 0..1023
    int d = gi >> 4, t8 = (gi & 15)*8;
    u16 tmp[8];
    #pragma unroll
    for (int j=0;j<8;++j) tmp[j] = f2u(sT[(t8+j)*65 + d]);
    *(short8*)&vT[((size_t)bk*DH + d)*SEQ + sc*128 + t8] = *(const short8*)tmp;
  }
}

// ---------------------------------------------------------------------------
// kv/kz per-chunk sums: block = (bk, c); thread m accumulates phik[t,m]*v[t,:]
// kv written TRANSPOSED [blk][d][m] (coalesced: lanes share d, consecutive m).
// ---------------------------------------------------------------------------
__global__ __launch_bounds__(256) void kvchunk_kernel(const bf16* __restrict__ phik,
    const float* __restrict__ vbuf, float* __restrict__ kv, float* __restrict__ kz)
{
  int blk = blockIdx.x; int bk = blk >> 4, c = blk & 15;
  const bf16* Kc = phik + ((size_t)bk*SEQ + c*128)*MFEAT;
  const float* Vc = vbuf + ((size_t)bk*SEQ + c*128)*DH;
  __shared__ float sV[128*64];
  for (int l=0;l<32;++l){ int idx = threadIdx.x + l*256; sV[idx] = Vc[idx]; }
  __syncthreads();
  int m = threadIdx.x;
  float acc[64] = {}; float az = 0.f;
  for (int t=0;t<128;++t){
    float ph = b2f(Kc[(size_t)t*MFEAT + m]);
    az += ph;
    const float4* vr = (const float4*)&sV[t*64];
    #pragma unroll
    for (int d4=0; d4<16; ++d4){
      float4 v4 = vr[d4];
      acc[d4*4+0] += ph*v4.x; acc[d4*4+1] += ph*v4.y;
      acc[d4*4+2] += ph*v4.z; acc[d4*4+3] += ph*v4.w;
    }
  }
  float* out = kv + (size_t)blk*MFEAT*DH;
  #pragma unroll
  for (int d=0; d<64; ++d) out[(size_t)d*MFEAT + m] = acc[d];
  kz[(size_t)blk*MFEAT + m] = az;
}

// exclusive prefix over chunk axis for BOTH kv and kz in one dispatch;
// writes bf16 prefix to ob (fp32 p unchanged).
// threads [0, 262144): kv (outer=bk 16, inner=MFEAT*DH, nc=16)
// threads [262144, 266240): kz (outer=bk 16, inner=MFEAT, nc=16)
__global__ void scan2_kernel(const float* __restrict__ pkv, u16* __restrict__ obkv,
                             const float* __restrict__ pkz, u16* __restrict__ obkz){
  int t = blockIdx.x*256 + threadIdx.x;
  const int TOTKV = 16*MFEAT*DH;
  if (t < TOTKV){
    int outer = t / (MFEAT*DH), rem = t - outer*(MFEAT*DH);
    const float* base = pkv + (size_t)outer*NCH*MFEAT*DH + rem;
    u16* obase = obkv + (size_t)outer*NCH*MFEAT*DH + rem;
    float run = 0.f;
    #pragma unroll
    for (int c=0;c<NCH;++c){
      float v = base[(size_t)c*MFEAT*DH];
      obase[(size_t)c*MFEAT*DH] = f2u(run);
      run += v;
    }
  } else {
    int t2 = t - TOTKV;
    if (t2 < 16*MFEAT){
      int outer = t2 / MFEAT, rem = t2 - outer*MFEAT;
      const float* base = pkz + (size_t)outer*NCH*MFEAT + rem;
      u16* obase = obkz + (size_t)outer*NCH*MFEAT + rem;
      float run = 0.f;
      #pragma unroll
      for (int c=0;c<NCH;++c){
        float v = base[(size_t)c*MFEAT];
        obase[(size_t)c*MFEAT] = f2u(run);
        run += v;
      }
    }
  }
}

// ---------------------------------------------------------------------------
// MFMA attention: block = (b,h,chunk). 4 waves, each owns 32 rows.
// P1/P3 fused over feat chunks of 32: S += Q*K^T, O += Q*[KVpre|KZpre]
// All staging async (cp16) from bf16 sources:
//   sKVT [80][32]: KVpre^T bf16 (kvpb [blk][d][m]) granule-XOR g^=d&3,
//                  pre-swizzled source; row 64 = KZpre (kzpb).
//   sVT  [80][128]: V^T bf16 (vT [bk][d][s]) granule-XOR g^=d&7, staged
//                  ONCE before the k0 loop (region untouched until P2);
//                  row 64 = ones (written in epilogue).
// mask S in regs -> P to LDS (bf16, stride 136); P2: O += P*[V|1]^T.
// z (col 64) = ez+iz -> divide -> store (b,s,h,d) bf16.
// ---------------------------------------------------------------------------
__global__ __launch_bounds__(256) void attn_mfma(
    const u16* __restrict__ phiq, const u16* __restrict__ phik,
    const u16* __restrict__ kvpb, const u16* __restrict__ kzpb,
    const u16* __restrict__ vT, u16* __restrict__ attnout)
{
  __shared__ __align__(16) u16 smem[27648];
  __shared__ float sZ[128];
  const int tid = threadIdx.x, lane = tid & 63, wave = tid >> 6;
  const int blk = blockIdx.x;
  const int c = blk & 15, h = (blk >> 4) & 31, b = blk >> 9;
  const int kvh = h >> 2;
  const int bkv = b*NKVH + kvh;
  const u16* Q   = phiq + (((size_t)(b*NHEAD+h)*SEQ) + c*128)*MFEAT;
  const u16* Kc  = phik + (((size_t)bkv*SEQ) + c*128)*MFEAT;
  const u16* KVb = kvpb + ((size_t)(bkv*NCH + c))*MFEAT*DH;   // [d][m] bf16
  const u16* KZb = kzpb + ((size_t)(bkv*NCH + c))*MFEAT;
  const u16* vTb = vT + (size_t)bkv*DH*SEQ;                    // [d][s] bf16

  u16* sQ   = smem;            // [128][32]
  u16* sK   = smem + 4096;     // [128][32]
  u16* sKVT = smem + 8192;     // [80][32]   (rows 65-79 unused)
  u16* sP   = smem;            // [128][136]
  u16* sVT  = smem + 17408;    // [80][128]  (rows 65-79 unused)

  f32x4 accS[2][8] = {};
  f32x4 accO[2][5] = {};

  // stage V^T rows 0-63 once, async (drains at first loop barrier);
  // source pre-swizzled: LDS[d][g] = vT[d][c*128 + ((g^(d&7))*8)..]
  #pragma unroll
  for (int i=0;i<4;++i){
    int gi = tid + i*256;          // 0..1023
    int d  = gi >> 4, g = gi & 15;
    cp16(&sVT[(i*256 + wave*64)*8],
         vTb + (size_t)d*SEQ + c*128 + ((g ^ (d&7))<<3));
  }

  const int ch0 = wave*64 + lane, ch1 = 256 + wave*64 + lane;
  const u16* gQ0 = Q  + (ch0>>2)*MFEAT + (ch0&3)*8;
  const u16* gQ1 = Q  + (ch1>>2)*MFEAT + (ch1&3)*8;
  const u16* gK0 = Kc + (ch0>>2)*MFEAT + (ch0&3)*8;
  const u16* gK1 = Kc + (ch1>>2)*MFEAT + (ch1&3)*8;
  u16* lQ0 = &sQ[(wave*64)*8];  u16* lQ1 = &sQ[(256+wave*64)*8];
  u16* lK0 = &sK[(wave*64)*8];  u16* lK1 = &sK[(256+wave*64)*8];

  // sKVT staging source: thread (wave,lane) -> row d = wave*16 + (lane>>2),
  // granule g = lane&3; LDS[d][g] = KVb[d][k0 + ((g^(d&3))*8)..]
  const int dKV = wave*16 + (lane>>2);
  const u16* gKVsrc = KVb + (size_t)dKV*MFEAT + (((lane&3) ^ (dKV&3))<<3);

  for (int k0 = 0; k0 < MFEAT; k0 += 32) {
    cp16(lQ0, gQ0 + k0); cp16(lQ1, gQ1 + k0);
    cp16(lK0, gK0 + k0); cp16(lK1, gK1 + k0);
    cp16(&sKVT[wave*512], gKVsrc + k0);
    if (tid < 4) cp16(&sKVT[2048], KZb + k0 + tid*8);
    __syncthreads();
    short8 af0, af1;
    const u16* pQ = &sQ[(wave*32 + (lane&15))*32 + (lane>>4)*8];
    af0 = *(const short8*)(pQ);
    af1 = *(const short8*)(pQ + 512);
    #pragma unroll
    for (int nt=0;nt<8;++nt){
      short8 bk = *(const short8*)&sK[(nt*16 + (lane&15))*32 + (lane>>4)*8];
      accS[0][nt] = MFMA16(af0, bk, accS[0][nt]);
      accS[1][nt] = MFMA16(af1, bk, accS[1][nt]);
    }
    #pragma unroll
    for (int nt=0;nt<5;++nt){
      int row = nt*16 + (lane&15);
      short8 bi = *(const short8*)&sKVT[row*32 + (((lane>>4) ^ (row&3))<<3)];
      accO[0][nt] = MFMA16(af0, bi, accO[0][nt]);
      accO[1][nt] = MFMA16(af1, bi, accO[1][nt]);
    }
    __syncthreads();
  }

  // mask + write P (bf16, stride 136); ones row for sVT
  #pragma unroll
  for (int mt=0;mt<2;++mt){
    int rowb = wave*32 + mt*16 + (lane>>4)*4;
    #pragma unroll
    for (int nt=0;nt<8;++nt){
      int col = nt*16 + (lane&15);
      #pragma unroll
      for (int rg=0;rg<4;++rg){
        int row = rowb + rg;
        float v = (col <= row) ? accS[mt][nt][rg] : 0.f;
        sP[row*136 + col] = f2u(v);
      }
    }
  }
  if (tid < 16){
    u16 ones[8] = {0x3F80,0x3F80,0x3F80,0x3F80,0x3F80,0x3F80,0x3F80,0x3F80};
    *(short8*)&sVT[64*128 + tid*8] = *(const short8*)ones;
  }
  __syncthreads();

  // P2: O += P @ [V|1]  (sVT granule-swizzled read)
  #pragma unroll
  for (int kc=0;kc<4;++kc){
    const u16* pP = &sP[(wave*32 + (lane&15))*136 + kc*32 + (lane>>4)*8];
    short8 pa0 = *(const short8*)(pP);
    short8 pa1 = *(const short8*)(pP + 16*136);
    #pragma unroll
    for (int nt=0;nt<5;++nt){
      int row = nt*16 + (lane&15);
      int g   = kc*4 + (lane>>4);
      short8 bv = *(const short8*)&sVT[row*128 + ((g ^ (row&7))<<3)];
      accO[0][nt] = MFMA16(pa0, bv, accO[0][nt]);
      accO[1][nt] = MFMA16(pa1, bv, accO[1][nt]);
    }
  }

  // z broadcast + divide + store
  if ((lane & 15) == 0){
    #pragma unroll
    for (int mt=0;mt<2;++mt){
      int rowb = wave*32 + mt*16 + (lane>>4)*4;
      #pragma unroll
      for (int rg=0;rg<4;++rg) sZ[rowb + rg] = accO[mt][4][rg];
    }
  }
  __syncthreads();
  const int d0 = lane & 15;
  #pragma unroll
  for (int mt=0;mt<2;++mt){
    int rowb = wave*32 + mt*16 + (lane>>4)*4;
    #pragma unroll
    for (int rg=0;rg<4;++rg){
      int row = rowb + rg;
      float inv = 1.0f / (sZ[row] + EPSF);
      int sg = c*128 + row;
      size_t ob = (((size_t)b*SEQ + sg)*NHEAD + h)*DH;
      #pragma unroll
      for (int nt=0;nt<4;++nt)
        attnout[ob + nt*16 + d0] = f2u(accO[mt][nt][rg] * inv);
    }
  }
}

// ---------------------------------------------------------------------------
extern "C" void kernel_launch(void* const* d_in, const int* in_sizes, int n_in,
                              void* d_out, int out_size, void* d_ws, size_t ws_size,
                              hipStream_t stream)
{
  const void* hidden = d_in[0];
  const void* cosg   = d_in[1];
  const void* sing   = d_in[2];
  const void* Wq     = d_in[3];
  const void* Wk     = d_in[4];
  const void* Wv     = d_in[5];
  const void* Wo     = d_in[6];
  const void* proj   = d_in[7];
  const unsigned* probe = (const unsigned*)d_in[1];

  float* ws = (float*)d_ws;
  // overlays (stream-order safe):
  //   [0, 8388608): xnq (until phi_mfma q); then kv/kz/rmaxk/stabk/vT/kvpb/kzpb
  float* xnq   = ws;                       // 8388608 f
  float* kv    = ws;                       // 4194304 f (after phi q)
  float* kz    = ws + 4194304;             //   65536 f
  float* rmaxk = ws + 4259840;             //   32768 f
  float* stabk = ws + 4292608;             //     256 f
  u16*   vT    = (u16*) (ws + 4292864);    //  2097152 u16 (after phi q)
  u16*   kvpb  = (u16*) (ws + 5341440);    //  4194304 u16
  u16*   kzpb  = (u16*) (ws + 7438592);    //    65536 u16
  float* xnk   = ws + 8388608;             // 2097152 f
  float* vbuf  = ws + 10485760;            // 2097152 f
  u16*   projb = (u16*) (ws + 12582912);   //   16384 bf16
  bf16*  phiq  = (bf16*)(ws + 12591104);   // 33554432 bf16
  bf16*  phik  = (bf16*)(ws + 29368320);   //  8388608 bf16
  u16*   hb    = (u16*) (ws + 33562624);   //  8388608 bf16 (hidden; attn later)
  u16*   attn  = (u16*) (ws + 33562624);   //  (same region, after QKV gemm)
  u16*   wqkv  = (u16*) (ws + 37756928);   //  6291456 bf16
  u16*   wob   = (u16*) (ws + 37756928);   //  (same region, after QKV gemm)

  // converts (vectorized): hidden, fused Wq|Wk|Wv, proj
  conv_kernel<<<4096, 256, 0, stream>>>(hidden, hb, probe);
  wconv_kernel<<<3072, 256, 0, stream>>>(Wq, Wk, Wv, wqkv, probe);
  conv_kernel<<<8,    256, 0, stream>>>(proj, projb, probe);

  // fused QKV projection + RoPE + dn (fp32 head-major out); 256x128 tiles
  gemm_mfma<<<dim3(24,16), 512, 0, stream>>>(hb, wqkv, xnq, xnk, vbuf, nullptr,
                                             2048, 3072, 1, cosg, sing, probe);
  // Wo convert (reuses wqkv region; ordered after QKV gemm)
  conv_kernel<<<2048, 256, 0, stream>>>(Wo, wob, probe);

  // phi features via MFMA
  phi_mfma<<<2048, 256, 0, stream>>>(xnq, projb, nullptr, nullptr, (u16*)phiq, 0);
  // V transpose to bf16 (xnq dead now; vT overlays its tail region)
  vtrans_kernel<<<256, 256, 0, stream>>>(vbuf, vT);
  phi_mfma<<<512,  256, 0, stream>>>(xnk, projb, rmaxk, nullptr, nullptr, 1);
  stab_reduce_kernel<<<16, 256, 0, stream>>>(rmaxk, stabk);
  phi_mfma<<<512,  256, 0, stream>>>(xnk, projb, nullptr, stabk, (u16*)phik, 2);

  // chunk kv/kz states (kv transposed [blk][d][m]) + fused exclusive prefix -> bf16
  kvchunk_kernel<<<256, 256, 0, stream>>>(phik, vbuf, kv, kz);
  scan2_kernel<<<1040, 256, 0, stream>>>(kv, kvpb, kz, kzpb);

  // MFMA attention (all-bf16 async staging)
  attn_mfma<<<1024, 256, 0, stream>>>((const u16*)phiq, (const u16*)phik,
                                      kvpb, kzpb, vT, attn);

  // output projection (out dtype follows input dtype); 256x128 tiles
  gemm_mfma<<<dim3(16,16), 512, 0, stream>>>(attn, wob, nullptr, nullptr, nullptr,
                                             d_out, 2048, 2048, 0, nullptr, nullptr, probe);
}